// Round 11
// baseline (589.623 us; speedup 1.0000x reference)
//
#include <hip/hip_runtime.h>

// RNNCell scan: T=512, B=16384, H=32.
// 4-BATCH/WAVE RELAYOUT (r10): 4 batches/wave -> 4096 waves = 4 waves/SIMD.
// r1/r7/r8/r9 triangulated: at 2 waves/SIMD the wall = ~1320 issue +
// ~680 dual-stall cy/step; issue cuts and chain cuts get absorbed, only
// MORE WAVES can cover the stall. Halving batches/wave doubles TLP at
// ~constant per-SIMD issue.
// Layout: bat = lane&3; lane owns h = {2*(lane>>2), +1} (2 h/lane).
// MFMA B-fragments via per-wave LDS round-trip (ds_write_b32 x2 +
// ds_read_b128 x2 per fragment pair, own 1KB region/wave, no barrier —
// in-wave lgkmcnt ordering): degree-4 lane fan-in with ZERO VALU cost.
// A-row permutation hc(m,i) = 8(m>>2)+2(m&3)+i puts lane's owned h at
// D-reg cc=(lane&15)>>2 of tile i; post-GEMM select = 3 cndmask/value.
// Reduce over the batch's 16 lanes (stride 4): rotation-sum
// (ror4+ror8+ror12, direction-convention-free) + permlane16/32 swaps.
// Store predicated to lanes 0-3 (was 16x dup-address stores).
// bf16 hi/lo trunc split, 3-deep MFMA accumulate (r8: flattening costs
// issue for no win). -log2e folded into GEMM1 A/bias; W3 into GEMM2 A.
// PACKED-F32 pointwise (v_pk_* VOP3P). p0 store deferred one iteration.
// NOTE: amdgpu_waves_per_eu is BANNED (r6: post-timing divergence);
// __launch_bounds__ is the verified-correct form.
// r10 fix: DPP ctrl must be an ICE -> rorNf is template<int CTRL>.

#define T_STEPS 512
#define B_TOT   16384
#define STRIDE_B 65536            // B_TOT * sizeof(float)

typedef __attribute__((ext_vector_type(8))) short short8;
typedef __attribute__((ext_vector_type(4))) float f32x4;
typedef __attribute__((ext_vector_type(2))) float f32x2;
typedef __attribute__((ext_vector_type(4))) int   i32x4;
typedef __attribute__((ext_vector_type(2))) unsigned int uint2v;

__device__ __forceinline__ short8 as_s8(i32x4 v) {
    union { i32x4 i; short8 s; } u; u.i = v; return u.s;
}

#define NLOG2E -1.44269504088896340736f
#define LN2     0.69314718055994530942f

// paired softplus + sigmoid sharing one exp each.
__device__ __forceinline__ void sp_sig2(f32x2 z, f32x2& sp, f32x2& sg) {
    const f32x2 zs = z * NLOG2E;
    f32x2 t;
    t[0] = __builtin_amdgcn_exp2f(zs[0]);
    t[1] = __builtin_amdgcn_exp2f(zs[1]);
    const f32x2 u = t + 1.0f;
    f32x2 r;
    r[0] = __builtin_amdgcn_rcpf(u[0]);
    r[1] = __builtin_amdgcn_rcpf(u[1]);
    sg = r;
    f32x2 lg;
    lg[0] = __builtin_amdgcn_logf(r[0]);
    lg[1] = __builtin_amdgcn_logf(r[1]);
    const f32x2 nl2 = {-LN2, -LN2};
    sp = __builtin_elementwise_fma(lg, nl2, z);
}

// paired sigmoid from pre-scaled zs = -log2e * z
__device__ __forceinline__ f32x2 sigm2v(f32x2 zs) {
    f32x2 t;
    t[0] = __builtin_amdgcn_exp2f(zs[0]);
    t[1] = __builtin_amdgcn_exp2f(zs[1]);
    const f32x2 u = t + 1.0f;
    f32x2 r;
    r[0] = __builtin_amdgcn_rcpf(u[0]);
    r[1] = __builtin_amdgcn_rcpf(u[1]);
    return r;
}

// exact trunc split of a pair -> one hi word + one lo word (2 bf16 each).
__device__ __forceinline__ void sp2tv(f32x2 x, int& hi, int& lo) {
    const unsigned u0 = __float_as_uint(x[0]);
    const unsigned u1 = __float_as_uint(x[1]);
    hi = (int)__builtin_amdgcn_perm(u1, u0, 0x07060302u);
    f32x2 h;
    h[0] = __uint_as_float(u0 & 0xffff0000u);
    h[1] = __uint_as_float(u1 & 0xffff0000u);
    const f32x2 l = x - h;
    lo = (int)__builtin_amdgcn_perm(__float_as_uint(l[1]), __float_as_uint(l[0]),
                                    0x07060302u);
}

// row rotations (within each 16-lane row) on the VALU pipe.
// DPP ctrl must be an integer-constant-expression -> template parameter.
template <int CTRL>
__device__ __forceinline__ float rorNf(float x) {
    return __int_as_float(
        __builtin_amdgcn_update_dpp(0, __float_as_int(x), CTRL, 0xF, 0xF, 1));
}
// class-sum over the stride-4 class within a 16-lane row:
// x + ror4 + ror8 + ror12 covers all 4 members regardless of direction.
__device__ __forceinline__ float rsum4(float x) {
    return ((x + rorNf<0x124>(x)) + rorNf<0x128>(x)) + rorNf<0x12C>(x);
}
// butterfly xor16 / xor32 sums via permlane swaps.
__device__ __forceinline__ float sum16(float x) {
    const uint2v r = __builtin_amdgcn_permlane16_swap(
        __float_as_uint(x), __float_as_uint(x), false, false);
    return __uint_as_float(r[0]) + __uint_as_float(r[1]);
}
__device__ __forceinline__ float sum32(float x) {
    const uint2v r = __builtin_amdgcn_permlane32_swap(
        __float_as_uint(x), __float_as_uint(x), false, false);
    return __uint_as_float(r[0]) + __uint_as_float(r[1]);
}

#define MFMA(A, B, C) __builtin_amdgcn_mfma_f32_16x16x32_bf16((A), (B), (C), 0, 0, 0)

__global__ __launch_bounds__(256, 4) void rnn_scan(
    const float* __restrict__ eps, const float* __restrict__ hs,
    const float* __restrict__ W1,  const float* __restrict__ b1,
    const float* __restrict__ W2,  const float* __restrict__ b2,
    const float* __restrict__ W3,  float* __restrict__ out)
{
    const int lane = threadIdx.x & 63;
    const int wv   = threadIdx.x >> 6;
    const int bat  = lane & 3;           // batch within wave (4)
    const int hg   = lane >> 2;          // h-pair group: h = 2*hg + i
    const int c    = lane & 15;          // MFMA row/col index
    const int q    = lane >> 4;          // MFMA quad (k-octet / D-row block)
    const int cc   = c >> 2;             // column-copy = D-reg index of owned h
    const int bidx = blockIdx.x * 16 + wv * 4 + bat;

    // per-wave LDS region: [0..63]=aH  [64..127]=aL  [128..191]=vH  [192..255]=vL
    __shared__ alignas(16) int lds_x[4][256];
    int* wbuf = lds_x[wv];
    const int wa = bat * 16 + hg;        // write slot (word idx)
    const int rb = (c & 3) * 16 + 4 * q; // read base: batch c&3, hg octet 4q..4q+3

    // owned-h weights (h = 2*hg + {0,1})
    const int h0 = 2 * hg;
    const f32x2 W1eP = {W1[h0],      W1[h0 + 1]};
    const f32x2 W1gP = {W1[32 + h0], W1[32 + h0 + 1]};
    const f32x2 b1P  = {b1[h0],      b1[h0 + 1]};

    // D-layout b2: tile i, reg r (row 4q+r) <-> h = 8q + 2r + i; pre-scaled.
    f32x4 B2V0, B2V1;
#pragma unroll
    for (int r = 0; r < 4; ++r) {
        B2V0[r] = b2[8 * q + 2 * r]     * NLOG2E;
        B2V1[r] = b2[8 * q + 2 * r + 1] * NLOG2E;
    }
    const f32x4 ZV = {0.f, 0.f, 0.f, 0.f};

    // A fragments, row-permuted hc(m,i) = 8*(m>>2) + 2*(m&3) + i.
    // A1 (GEMM1, z2 = W2^T a1 + b2) pre-scaled by -log2e; A2 has W3 folded.
    i32x4 A1h[2], A1l[2], A2h[2], A2l[2];
#pragma unroll
    for (int i = 0; i < 2; ++i) {
        const int hc = 8 * (c >> 2) + 2 * (c & 3) + i;
#pragma unroll
        for (int p = 0; p < 4; ++p) {
            int th, tl;
            const int k0 = 8 * q + 2 * p, k1 = k0 + 1;
            const f32x2 x = {W2[k0 * 32 + hc] * NLOG2E,
                             W2[k1 * 32 + hc] * NLOG2E};
            sp2tv(x, th, tl);
            A1h[i][p] = th; A1l[i][p] = tl;
            const f32x2 y = {W2[hc * 32 + k0] * W3[k0],
                             W2[hc * 32 + k1] * W3[k1]};
            sp2tv(y, th, tl);
            A2h[i][p] = th; A2l[i][p] = tl;
        }
    }

    const bool cb0 = (cc & 1) != 0;      // owned-h D-reg select bits
    const bool cb1 = (cc & 2) != 0;
#define SELCC(v) (cb1 ? (cb0 ? (v)[3] : (v)[2]) : (cb0 ? (v)[1] : (v)[0]))

    float gamma = 0.0f;
    float h_cur = hs[bidx];
    f32x2 pre;
    {
        const float e0 = eps[bidx];
        const f32x2 ev = {e0, e0};
        pre = __builtin_elementwise_fma(ev, W1eP, b1P);
    }
    int voff_ld = bidx * 4 + STRIDE_B;   // loads for step t+1
    int voff_st = bidx * 4;              // store for step t-1
    float p0_pend = 0.0f;

#define STEP_BODY(PF, ST)                                                      \
    {                                                                          \
        if (ST) {                                                              \
            if (lane < 4) *(float*)((char*)out + voff_st) = p0_pend;           \
            voff_st += STRIDE_B;                                               \
        }                                                                      \
        float e_nxt = 0.f, h_nxt = 0.f;                                        \
        if (PF) {                                                              \
            e_nxt = *(const float*)((const char*)eps + voff_ld);               \
            h_nxt = *(const float*)((const char*)hs + voff_ld);                \
            voff_ld += STRIDE_B;                                               \
        }                                                                      \
        /* z1 = pre + gamma*W1g; a1 = softplus, g1 = sigmoid (2 h/lane) */     \
        const f32x2 gv = {gamma, gamma};                                       \
        const f32x2 z1p = __builtin_elementwise_fma(gv, W1gP, pre);            \
        f32x2 a1p, g1p;                                                        \
        sp_sig2(z1p, a1p, g1p);                                                \
        int Ha, La;                                                            \
        sp2tv(a1p, Ha, La);                                                    \
        /* B fragment via per-wave LDS round-trip (no barrier needed) */       \
        wbuf[wa]      = Ha;                                                    \
        wbuf[64 + wa] = La;                                                    \
        const i32x4 bh = *reinterpret_cast<const i32x4*>(&wbuf[rb]);           \
        const i32x4 bl = *reinterpret_cast<const i32x4*>(&wbuf[64 + rb]);      \
        /* GEMM1: zs2 = -log2e*(W2^T a1 + b2); 3-deep chains */                \
        const short8 Bh = as_s8(bh), Bl = as_s8(bl);                           \
        f32x4 zA = MFMA(as_s8(A1h[0]), Bh, B2V0);                              \
        f32x4 zB = MFMA(as_s8(A1h[1]), Bh, B2V1);                              \
        zA = MFMA(as_s8(A1h[0]), Bl, zA);                                      \
        zB = MFMA(as_s8(A1h[1]), Bl, zB);                                      \
        zA = MFMA(as_s8(A1l[0]), Bh, zA);                                      \
        zB = MFMA(as_s8(A1l[1]), Bh, zB);                                      \
        /* owned-h select (reg cc of tile i); v2 = sigm(z2) (W3 in A2) */      \
        const f32x2 zsel = {SELCC(zA), SELCC(zB)};                             \
        const f32x2 v2p = sigm2v(zsel);                                        \
        int Hv, Lv;                                                            \
        sp2tv(v2p, Hv, Lv);                                                    \
        wbuf[128 + wa] = Hv;                                                   \
        wbuf[192 + wa] = Lv;                                                   \
        const i32x4 vh = *reinterpret_cast<const i32x4*>(&wbuf[128 + rb]);     \
        const i32x4 vl = *reinterpret_cast<const i32x4*>(&wbuf[192 + rb]);     \
        /* GEMM2: s = W2 diag(W3) sig; 3-deep chains */                        \
        const short8 Vh = as_s8(vh), Vl = as_s8(vl);                           \
        f32x4 sA = MFMA(as_s8(A2h[0]), Vh, ZV);                                \
        f32x4 sB = MFMA(as_s8(A2h[1]), Vh, ZV);                                \
        sA = MFMA(as_s8(A2h[0]), Vl, sA);                                      \
        sB = MFMA(as_s8(A2h[1]), Vl, sB);                                      \
        sA = MFMA(as_s8(A2l[0]), Vh, sA);                                      \
        sB = MFMA(as_s8(A2l[1]), Vh, sB);                                      \
        /* epilogue: v1 = g1.*s; partial p = v1@W1^T (2 h/lane) */             \
        const f32x2 ssel = {SELCC(sA), SELCC(sB)};                             \
        const f32x2 vP = g1p * ssel;                                           \
        const f32x2 P0 = vP * W1eP;                                            \
        const f32x2 P1 = vP * W1gP;                                            \
        float p0 = P0[0] + P0[1];                                              \
        float p1 = P1[0] + P1[1];                                              \
        /* reduce over the batch's 16 lanes (stride 4): rotation-sum */        \
        /* within rows, then xor16/xor32 permlane swaps — all VALU */          \
        p1 = rsum4(p1);  p0 = rsum4(p0);                                       \
        p1 = sum16(p1);  p0 = sum16(p0);                                       \
        p1 = sum32(p1);  p0 = sum32(p0);                                       \
        p0_pend = p0;                    /* store deferred to next iter */     \
        gamma = fmaf(h_cur, -p1, gamma);                                       \
        h_cur = h_nxt;                                                         \
        if (PF) {                                                              \
            const f32x2 ev = {e_nxt, e_nxt};                                   \
            pre = __builtin_elementwise_fma(ev, W1eP, b1P);                    \
        }                                                                      \
    }

    STEP_BODY(1, 0)                                      // t = 0
    for (int t = 1; t < T_STEPS - 1; ++t) STEP_BODY(1, 1)
    STEP_BODY(0, 1)                                      // t = 511
    if (lane < 4) *(float*)((char*)out + voff_st) = p0_pend;  // flush t = 511
#undef STEP_BODY
#undef SELCC
}

extern "C" void kernel_launch(void* const* d_in, const int* in_sizes, int n_in,
                              void* d_out, int out_size, void* d_ws, size_t ws_size,
                              hipStream_t stream) {
    const float* eps = (const float*)d_in[0];
    const float* hs  = (const float*)d_in[1];
    const float* W1  = (const float*)d_in[2];
    const float* b1  = (const float*)d_in[3];
    const float* W2  = (const float*)d_in[4];
    const float* b2  = (const float*)d_in[5];
    const float* W3  = (const float*)d_in[6];
    float* out = (float*)d_out;

    // 16 batches per 256-thread block (4 waves x 4) -> 1024 blocks,
    // 4096 waves = 4 waves/SIMD (4 blocks/CU)
    dim3 grid(B_TOT / 16), block(256);
    hipLaunchKernelGGL(rnn_scan, grid, block, 0, stream,
                       eps, hs, W1, b1, W2, b2, W3, out);
}

// Round 12
// 485.068 us; speedup vs baseline: 1.2155x; 1.2155x over previous
//
#include <hip/hip_runtime.h>

// RNNCell scan: T=512, B=16384, H=32.
// DUAL-GROUP ILP (r12): 16 batches/wave as TWO independent 8-batch groups
// -> 1024 waves = 1 wave/SIMD, 2-way in-wave ILP.
// Rationale: r11 proved more concurrency covers the stalls (pipe-busy
// 87->91%) but its 4-batch fragments doubled MFMA/batch and added LDS
// conflicts (net -40%). This keeps r7's work-efficient 8-batch fragment
// scheme (12 MFMAs per group-step, zero-LDS DPP shuffles, shared weight
// fragments) and replaces dynamic 2-wave sharing with a static 2-group
// interleave inside one wave: the compiler deterministically fills each
// group's trans/MFMA latency with the other group's issue — no lockstep.
// Per-group structure == r7: compact layout (bat=lane&7, h=4*(lane>>3)+i),
// ror8-DPP + cndmask B-fragments, bf16 hi/lo trunc split, 3-deep MFMA
// accumulate (r8: flattening costs issue for no win), -log2e folded into
// GEMM1 A/bias, W3 folded into GEMM2 A, packed-f32 pointwise (v_pk_*),
// ror8+permlane16/32 reduce, p0 stores deferred one iteration.
// Group B = batches bidx+8; its loads/stores use +32B immediate offsets.
// NOTE: amdgpu_waves_per_eu is BANNED (r6: post-timing divergence);
// __launch_bounds__(256,1) allows the ~150-200 VGPR this needs.

#define T_STEPS 512
#define B_TOT   16384
#define STRIDE_B 65536            // B_TOT * sizeof(float)

typedef __attribute__((ext_vector_type(8))) short short8;
typedef __attribute__((ext_vector_type(4))) float f32x4;
typedef __attribute__((ext_vector_type(2))) float f32x2;
typedef __attribute__((ext_vector_type(4))) int   i32x4;
typedef __attribute__((ext_vector_type(2))) unsigned int uint2v;

__device__ __forceinline__ short8 as_s8(i32x4 v) {
    union { i32x4 i; short8 s; } u; u.i = v; return u.s;
}

#define NLOG2E -1.44269504088896340736f
#define LN2     0.69314718055994530942f

// paired softplus + sigmoid sharing one exp each.
__device__ __forceinline__ void sp_sig2(f32x2 z, f32x2& sp, f32x2& sg) {
    const f32x2 zs = z * NLOG2E;
    f32x2 t;
    t[0] = __builtin_amdgcn_exp2f(zs[0]);
    t[1] = __builtin_amdgcn_exp2f(zs[1]);
    const f32x2 u = t + 1.0f;
    f32x2 r;
    r[0] = __builtin_amdgcn_rcpf(u[0]);
    r[1] = __builtin_amdgcn_rcpf(u[1]);
    sg = r;
    f32x2 lg;
    lg[0] = __builtin_amdgcn_logf(r[0]);
    lg[1] = __builtin_amdgcn_logf(r[1]);
    const f32x2 nl2 = {-LN2, -LN2};
    sp = __builtin_elementwise_fma(lg, nl2, z);
}

// paired sigmoid from pre-scaled zs = -log2e * z
__device__ __forceinline__ f32x2 sigm2v(f32x2 zs) {
    f32x2 t;
    t[0] = __builtin_amdgcn_exp2f(zs[0]);
    t[1] = __builtin_amdgcn_exp2f(zs[1]);
    const f32x2 u = t + 1.0f;
    f32x2 r;
    r[0] = __builtin_amdgcn_rcpf(u[0]);
    r[1] = __builtin_amdgcn_rcpf(u[1]);
    return r;
}

// exact trunc split of a pair, v_perm packing; residual sub packed.
__device__ __forceinline__ void sp2tv(f32x2 x, int& hi, int& lo) {
    const unsigned u0 = __float_as_uint(x[0]);
    const unsigned u1 = __float_as_uint(x[1]);
    hi = (int)__builtin_amdgcn_perm(u1, u0, 0x07060302u);
    f32x2 h;
    h[0] = __uint_as_float(u0 & 0xffff0000u);
    h[1] = __uint_as_float(u1 & 0xffff0000u);
    const f32x2 l = x - h;
    lo = (int)__builtin_amdgcn_perm(__float_as_uint(l[1]), __float_as_uint(l[0]),
                                    0x07060302u);
}

// row_ror:8 — swap the two 8-lane halves of each 16-lane row (VALU pipe)
__device__ __forceinline__ int ror8(int x) {
    return __builtin_amdgcn_update_dpp(0, x, 0x128, 0xF, 0xF, 1);
}
__device__ __forceinline__ float ror8f(float x) {
    return __int_as_float(ror8(__float_as_int(x)));
}

// butterfly xor16 / xor32 sums via permlane swaps.
__device__ __forceinline__ float sum16(float x) {
    const uint2v r = __builtin_amdgcn_permlane16_swap(
        __float_as_uint(x), __float_as_uint(x), false, false);
    return __uint_as_float(r[0]) + __uint_as_float(r[1]);
}
__device__ __forceinline__ float sum32(float x) {
    const uint2v r = __builtin_amdgcn_permlane32_swap(
        __float_as_uint(x), __float_as_uint(x), false, false);
    return __uint_as_float(r[0]) + __uint_as_float(r[1]);
}

#define MFMA(A, B, C) __builtin_amdgcn_mfma_f32_16x16x32_bf16((A), (B), (C), 0, 0, 0)

__global__ __launch_bounds__(256, 1) void rnn_scan(
    const float* __restrict__ eps, const float* __restrict__ hs,
    const float* __restrict__ W1,  const float* __restrict__ b1,
    const float* __restrict__ W2,  const float* __restrict__ b2,
    const float* __restrict__ W3,  float* __restrict__ out)
{
    const int lane = threadIdx.x & 63;
    const int wv   = threadIdx.x >> 6;
    const int bat  = lane & 7;           // batch within group
    const int hg   = lane >> 3;          // compact h-group: h = 4*hg + i
    const int c    = lane & 15;          // MFMA column
    const int q    = lane >> 4;          // MFMA quad
    const int bidx = blockIdx.x * 64 + wv * 16 + bat;   // group A batch
    // group B batch = bidx + 8  (+32 bytes on every per-batch address)

    // shared compact-layout weights (h = 4*hg + {0,1} / {2,3})
    const int h0 = 4 * hg;
    const f32x2 W1eP0 = {W1[h0 + 0],      W1[h0 + 1]};
    const f32x2 W1eP1 = {W1[h0 + 2],      W1[h0 + 3]};
    const f32x2 W1gP0 = {W1[32 + h0 + 0], W1[32 + h0 + 1]};
    const f32x2 W1gP1 = {W1[32 + h0 + 2], W1[32 + h0 + 3]};
    const f32x2 b1Pa  = {b1[h0 + 0],      b1[h0 + 1]};
    const f32x2 b1Pb  = {b1[h0 + 2],      b1[h0 + 3]};

    // D-layout b2 (h = 8q + i), pre-scaled by -log2e (shared MFMA C-seed).
    f32x4 B2V0, B2V1;
#pragma unroll
    for (int i = 0; i < 4; ++i) {
        B2V0[i] = b2[8 * q + i] * NLOG2E;
        B2V1[i] = b2[8 * q + 4 + i] * NLOG2E;
    }
    const f32x4 ZV = {0.f, 0.f, 0.f, 0.f};

    // shared A fragments (hi/lo trunc split), rows h(m,t)=8*(m>>2)+4t+(m&3).
    i32x4 A1h[2], A1l[2], A2h[2], A2l[2];
#pragma unroll
    for (int t = 0; t < 2; ++t) {
        const int hc = 8 * (c >> 2) + 4 * t + (c & 3);
#pragma unroll
        for (int p = 0; p < 4; ++p) {
            int th, tl;
            const int k0 = 8 * q + 2 * p, k1 = k0 + 1;
            const f32x2 x = {W2[k0 * 32 + hc] * NLOG2E,
                             W2[k1 * 32 + hc] * NLOG2E};
            sp2tv(x, th, tl);
            A1h[t][p] = th; A1l[t][p] = tl;
            const f32x2 y = {W2[hc * 32 + k0] * W3[k0],
                             W2[hc * 32 + k1] * W3[k1]};
            sp2tv(y, th, tl);
            A2h[t][p] = th; A2l[t][p] = tl;
        }
    }

    const bool hiHalf = (c & 8) != 0;
    const bool tsel   = (hg & 1) != 0;

    // per-group recurrence state
    float gmA = 0.0f, gmB = 0.0f;
    float hcA = hs[bidx], hcB = hs[bidx + 8];
    f32x2 preA0, preA1, preB0, preB1;
    {
        const float eA = eps[bidx], eB = eps[bidx + 8];
        const f32x2 evA = {eA, eA}, evB = {eB, eB};
        preA0 = __builtin_elementwise_fma(evA, W1eP0, b1Pa);
        preA1 = __builtin_elementwise_fma(evA, W1eP1, b1Pb);
        preB0 = __builtin_elementwise_fma(evB, W1eP0, b1Pa);
        preB1 = __builtin_elementwise_fma(evB, W1eP1, b1Pb);
    }
    int voff_ld = bidx * 4 + STRIDE_B;
    int voff_st = bidx * 4;
    float pdA = 0.0f, pdB = 0.0f;

// builds an MFMA B-fragment pair from compact-layout hi/lo words
#define FRAGPAIR(FH, FL, H0_, H1_, L0_, L1_)                                   \
    {                                                                          \
        const int rH0 = ror8(H0_), rH1 = ror8(H1_);                            \
        const int rL0 = ror8(L0_), rL1 = ror8(L1_);                            \
        FH[0] = hiHalf ? rH0 : H0_;  FH[1] = hiHalf ? rH1 : H1_;               \
        FH[2] = hiHalf ? H0_ : rH0;  FH[3] = hiHalf ? H1_ : rH1;               \
        FL[0] = hiHalf ? rL0 : L0_;  FL[1] = hiHalf ? rL1 : L1_;               \
        FL[2] = hiHalf ? L0_ : rL0;  FL[3] = hiHalf ? L1_ : rL1;               \
    }

#define STEP_BODY(PF, ST)                                                      \
    {                                                                          \
        if (ST) {                                                              \
            *(float*)((char*)out + voff_st)      = pdA;                        \
            *(float*)((char*)out + voff_st + 32) = pdB;                        \
            voff_st += STRIDE_B;                                               \
        }                                                                      \
        float eA = 0.f, eB = 0.f, hA = 0.f, hB = 0.f;                          \
        if (PF) {                                                              \
            eA = *(const float*)((const char*)eps + voff_ld);                  \
            eB = *(const float*)((const char*)eps + voff_ld + 32);             \
            hA = *(const float*)((const char*)hs  + voff_ld);                  \
            hB = *(const float*)((const char*)hs  + voff_ld + 32);             \
            voff_ld += STRIDE_B;                                               \
        }                                                                      \
        /* z1 = pre + gamma*W1g; softplus+sigmoid — groups interleaved */      \
        const f32x2 gvA = {gmA, gmA}, gvB = {gmB, gmB};                        \
        const f32x2 zpA0 = __builtin_elementwise_fma(gvA, W1gP0, preA0);       \
        const f32x2 zpB0 = __builtin_elementwise_fma(gvB, W1gP0, preB0);       \
        const f32x2 zpA1 = __builtin_elementwise_fma(gvA, W1gP1, preA1);       \
        const f32x2 zpB1 = __builtin_elementwise_fma(gvB, W1gP1, preB1);       \
        f32x2 aA0, gA0, aA1, gA1, aB0, gB0, aB1, gB1;                          \
        sp_sig2(zpA0, aA0, gA0);                                               \
        sp_sig2(zpB0, aB0, gB0);                                               \
        sp_sig2(zpA1, aA1, gA1);                                               \
        sp_sig2(zpB1, aB1, gB1);                                               \
        int HA0, LA0, HA1, LA1, HB0, LB0, HB1, LB1;                            \
        sp2tv(aA0, HA0, LA0);  sp2tv(aB0, HB0, LB0);                           \
        sp2tv(aA1, HA1, LA1);  sp2tv(aB1, HB1, LB1);                           \
        i32x4 bhA, blA, bhB, blB;                                              \
        FRAGPAIR(bhA, blA, HA0, HA1, LA0, LA1)                                 \
        FRAGPAIR(bhB, blB, HB0, HB1, LB0, LB1)                                 \
        /* GEMM1 (both groups interleaved; 3-deep chains per group) */         \
        const short8 BhA = as_s8(bhA), BlA = as_s8(blA);                       \
        const short8 BhB = as_s8(bhB), BlB = as_s8(blB);                       \
        f32x4 z0A = MFMA(as_s8(A1h[0]), BhA, B2V0);                            \
        f32x4 z0B = MFMA(as_s8(A1h[0]), BhB, B2V0);                            \
        f32x4 z1A = MFMA(as_s8(A1h[1]), BhA, B2V1);                            \
        f32x4 z1B = MFMA(as_s8(A1h[1]), BhB, B2V1);                            \
        z0A = MFMA(as_s8(A1h[0]), BlA, z0A);                                   \
        z0B = MFMA(as_s8(A1h[0]), BlB, z0B);                                   \
        z1A = MFMA(as_s8(A1h[1]), BlA, z1A);                                   \
        z1B = MFMA(as_s8(A1h[1]), BlB, z1B);                                   \
        z0A = MFMA(as_s8(A1l[0]), BhA, z0A);                                   \
        z0B = MFMA(as_s8(A1l[0]), BhB, z0B);                                   \
        z1A = MFMA(as_s8(A1l[1]), BhA, z1A);                                   \
        z1B = MFMA(as_s8(A1l[1]), BhB, z1B);                                   \
        /* tile-select + sigmoid (W3 folded into A2) — interleaved */          \
        const f32x2 zsA0 = {tsel ? z1A[0] : z0A[0], tsel ? z1A[1] : z0A[1]};   \
        const f32x2 zsB0 = {tsel ? z1B[0] : z0B[0], tsel ? z1B[1] : z0B[1]};   \
        const f32x2 zsA1 = {tsel ? z1A[2] : z0A[2], tsel ? z1A[3] : z0A[3]};   \
        const f32x2 zsB1 = {tsel ? z1B[2] : z0B[2], tsel ? z1B[3] : z0B[3]};   \
        const f32x2 vA0 = sigm2v(zsA0);                                        \
        const f32x2 vB0 = sigm2v(zsB0);                                        \
        const f32x2 vA1 = sigm2v(zsA1);                                        \
        const f32x2 vB1 = sigm2v(zsB1);                                        \
        sp2tv(vA0, HA0, LA0);  sp2tv(vB0, HB0, LB0);                           \
        sp2tv(vA1, HA1, LA1);  sp2tv(vB1, HB1, LB1);                           \
        i32x4 vhA, vlA, vhB, vlB;                                              \
        FRAGPAIR(vhA, vlA, HA0, HA1, LA0, LA1)                                 \
        FRAGPAIR(vhB, vlB, HB0, HB1, LB0, LB1)                                 \
        /* GEMM2 (both groups interleaved) */                                  \
        const short8 VhA = as_s8(vhA), VlA = as_s8(vlA);                       \
        const short8 VhB = as_s8(vhB), VlB = as_s8(vlB);                       \
        f32x4 s0A = MFMA(as_s8(A2h[0]), VhA, ZV);                              \
        f32x4 s0B = MFMA(as_s8(A2h[0]), VhB, ZV);                              \
        f32x4 s1A = MFMA(as_s8(A2h[1]), VhA, ZV);                              \
        f32x4 s1B = MFMA(as_s8(A2h[1]), VhB, ZV);                              \
        s0A = MFMA(as_s8(A2h[0]), VlA, s0A);                                   \
        s0B = MFMA(as_s8(A2h[0]), VlB, s0B);                                   \
        s1A = MFMA(as_s8(A2h[1]), VlA, s1A);                                   \
        s1B = MFMA(as_s8(A2h[1]), VlB, s1B);                                   \
        s0A = MFMA(as_s8(A2l[0]), VhA, s0A);                                   \
        s0B = MFMA(as_s8(A2l[0]), VhB, s0B);                                   \
        s1A = MFMA(as_s8(A2l[1]), VhA, s1A);                                   \
        s1B = MFMA(as_s8(A2l[1]), VhB, s1B);                                   \
        /* epilogue: v1 = g1.*s; p = v1@W1^T — interleaved */                  \
        const f32x2 ssA0 = {tsel ? s1A[0] : s0A[0], tsel ? s1A[1] : s0A[1]};   \
        const f32x2 ssB0 = {tsel ? s1B[0] : s0B[0], tsel ? s1B[1] : s0B[1]};   \
        const f32x2 ssA1 = {tsel ? s1A[2] : s0A[2], tsel ? s1A[3] : s0A[3]};   \
        const f32x2 ssB1 = {tsel ? s1B[2] : s0B[2], tsel ? s1B[3] : s0B[3]};   \
        const f32x2 wA0 = gA0 * ssA0, wA1 = gA1 * ssA1;                        \
        const f32x2 wB0 = gB0 * ssB0, wB1 = gB1 * ssB1;                        \
        f32x2 P0A = wA0 * W1eP0;                                               \
        f32x2 P0B = wB0 * W1eP0;                                               \
        P0A = __builtin_elementwise_fma(wA1, W1eP1, P0A);                      \
        P0B = __builtin_elementwise_fma(wB1, W1eP1, P0B);                      \
        f32x2 P1A = wA0 * W1gP0;                                               \
        f32x2 P1B = wB0 * W1gP0;                                               \
        P1A = __builtin_elementwise_fma(wA1, W1gP1, P1A);                      \
        P1B = __builtin_elementwise_fma(wB1, W1gP1, P1B);                      \
        float p0A = P0A[0] + P0A[1], p1A = P1A[0] + P1A[1];                    \
        float p0B = P0B[0] + P0B[1], p1B = P1B[0] + P1B[1];                    \
        /* 8-lane reduce (xor8 DPP, xor16/xor32 permlane) — interleaved */     \
        p1A += ror8f(p1A);  p1B += ror8f(p1B);                                 \
        p0A += ror8f(p0A);  p0B += ror8f(p0B);                                 \
        p1A = sum16(p1A);   p1B = sum16(p1B);                                  \
        p0A = sum16(p0A);   p0B = sum16(p0B);                                  \
        p1A = sum32(p1A);   p1B = sum32(p1B);                                  \
        p0A = sum32(p0A);   p0B = sum32(p0B);                                  \
        pdA = p0A;  pdB = p0B;                                                 \
        gmA = fmaf(hcA, -p1A, gmA);                                            \
        gmB = fmaf(hcB, -p1B, gmB);                                            \
        hcA = hA;  hcB = hB;                                                   \
        if (PF) {                                                              \
            const f32x2 evA = {eA, eA}, evB = {eB, eB};                        \
            preA0 = __builtin_elementwise_fma(evA, W1eP0, b1Pa);               \
            preB0 = __builtin_elementwise_fma(evB, W1eP0, b1Pa);               \
            preA1 = __builtin_elementwise_fma(evA, W1eP1, b1Pb);               \
            preB1 = __builtin_elementwise_fma(evB, W1eP1, b1Pb);               \
        }                                                                      \
    }

    STEP_BODY(1, 0)                                      // t = 0
    for (int t = 1; t < T_STEPS - 1; ++t) STEP_BODY(1, 1)
    STEP_BODY(0, 1)                                      // t = 511
    *(float*)((char*)out + voff_st)      = pdA;          // flush t = 511
    *(float*)((char*)out + voff_st + 32) = pdB;
#undef STEP_BODY
#undef FRAGPAIR
}

extern "C" void kernel_launch(void* const* d_in, const int* in_sizes, int n_in,
                              void* d_out, int out_size, void* d_ws, size_t ws_size,
                              hipStream_t stream) {
    const float* eps = (const float*)d_in[0];
    const float* hs  = (const float*)d_in[1];
    const float* W1  = (const float*)d_in[2];
    const float* b1  = (const float*)d_in[3];
    const float* W2  = (const float*)d_in[4];
    const float* b2  = (const float*)d_in[5];
    const float* W3  = (const float*)d_in[6];
    float* out = (float*)d_out;

    // 64 batches per 256-thread block (4 waves x 2 groups x 8) ->
    // 256 blocks = 1024 waves = 1 wave/SIMD, 2-way ILP inside each wave.
    dim3 grid(B_TOT / 64), block(256);
    hipLaunchKernelGGL(rnn_scan, grid, block, 0, stream,
                       eps, hs, W1, b1, W2, b2, W3, out);
}